// Round 5
// baseline (5684.563 us; speedup 1.0000x reference)
//
#include <hip/hip_runtime.h>
#include <math.h>

// Problem constants: B=64, T=2048, D=128, H=100, F=300
constexpr int H_ = 100;
constexpr int D_ = 128;
constexpr int F_ = 300;
constexpr int T_ = 2048;
constexpr int B_ = 64;
constexpr int G_ = 4 * H_;   // 400 gate rows
constexpr long M_ = (long)B_ * T_;   // 131072 rows

#define KEEP4(v) asm volatile("" : "+v"(v.x), "+v"(v.y), "+v"(v.z), "+v"(v.w))

static __device__ __forceinline__ float fast_rcp(float x) {
    return __builtin_amdgcn_rcpf(x);
}
static __device__ __forceinline__ float sigmoid_f(float u) {
    return fast_rcp(1.f + __expf(-u));   // inf-safe both directions
}
static __device__ __forceinline__ float tanh_safe(float c) {
    return fmaf(-2.f, fast_rcp(__expf(2.f * c) + 1.f), 1.f);
}

// ---------------------------------------------------------------------------
// Generic 128x128-tile f32 GEMM:  Out[m, n] = act( A[m,:K] . W[n,:K] + bias )
// 256 threads = 4 waves (2x2), lane tile 8x8. Both operands staged TRANSPOSED
// in LDS ([k][m] / [k][n]) so fragment reads are 2 contiguous b128 each:
// 4 LDS instr -> 64 FMA per lane per k (8 FMA per LDS instr vs 4/1 before).
// ---------------------------------------------------------------------------
template<int KTOT, int KB, int IN_LD, int W_LD, int OUT_LD, int N_REAL,
         int WK_REAL, bool RELU_IN, bool RELU_OUT, bool SKIP_PAD_WRITE, bool BIAS2>
__global__ __launch_bounds__(256, 2) void gemm128(
    const float* __restrict__ Ain, const float* __restrict__ Wm,
    const float* __restrict__ bias, const float* __restrict__ bias2,
    float* __restrict__ Out)
{
    __shared__ float as[KB][132];
    __shared__ float bs[KB][132];
    const int tid  = threadIdx.x;
    const int lane = tid & 63;
    const int wave = tid >> 6;
    const int row0 = (wave >> 1) * 64 + (lane >> 3) * 8;  // within block tile
    const int col0 = (wave & 1) * 64 + (lane & 7) * 8;
    const long rb  = (long)blockIdx.x * 128;
    const int  cb  = blockIdx.y * 128;
    constexpr int K4 = KB / 4;

    float acc[8][8];
    #pragma unroll
    for (int i = 0; i < 8; ++i)
        #pragma unroll
        for (int j = 0; j < 8; ++j) acc[i][j] = 0.f;

    for (int kb = 0; kb < KTOT; kb += KB) {
        // stage A tile transposed: as[k][row]
        for (int idx = tid; idx < 128 * K4; idx += 256) {
            int row = idx / K4, k4 = idx % K4;
            float4 v = *(const float4*)&Ain[(rb + row) * (long)IN_LD + kb + 4 * k4];
            if constexpr (RELU_IN) {
                v.x = fmaxf(v.x, 0.f); v.y = fmaxf(v.y, 0.f);
                v.z = fmaxf(v.z, 0.f); v.w = fmaxf(v.w, 0.f);
            }
            as[4*k4+0][row] = v.x; as[4*k4+1][row] = v.y;
            as[4*k4+2][row] = v.z; as[4*k4+3][row] = v.w;
        }
        // stage W tile transposed: bs[k][col], zero-fill col/k padding
        for (int idx = tid; idx < 128 * K4; idx += 256) {
            int col = idx / K4, k4 = idx % K4;
            int gc = cb + col;
            float4 v = make_float4(0.f, 0.f, 0.f, 0.f);
            if (gc < N_REAL && (WK_REAL == KTOT || kb + 4 * k4 < WK_REAL))
                v = *(const float4*)&Wm[(long)gc * W_LD + kb + 4 * k4];
            bs[4*k4+0][col] = v.x; bs[4*k4+1][col] = v.y;
            bs[4*k4+2][col] = v.z; bs[4*k4+3][col] = v.w;
        }
        __syncthreads();

        #pragma unroll
        for (int k = 0; k < KB; ++k) {
            float4 a0 = *(const float4*)&as[k][row0];
            float4 a1 = *(const float4*)&as[k][row0 + 4];
            float4 b0 = *(const float4*)&bs[k][col0];
            float4 b1 = *(const float4*)&bs[k][col0 + 4];
            const float av[8] = {a0.x, a0.y, a0.z, a0.w, a1.x, a1.y, a1.z, a1.w};
            const float bv[8] = {b0.x, b0.y, b0.z, b0.w, b1.x, b1.y, b1.z, b1.w};
            #pragma unroll
            for (int i = 0; i < 8; ++i)
                #pragma unroll
                for (int j = 0; j < 8; ++j)
                    acc[i][j] = fmaf(av[i], bv[j], acc[i][j]);
        }
        __syncthreads();
    }

    // epilogue: bias (+bias2), optional relu; pad cols write 0 (or skip)
    #pragma unroll
    for (int i = 0; i < 8; ++i) {
        const long obase = (rb + row0 + i) * (long)OUT_LD + cb;
        #pragma unroll
        for (int j4 = 0; j4 < 2; ++j4) {
            const int c0 = col0 + 4 * j4;
            if (SKIP_PAD_WRITE && (cb + c0) >= N_REAL) continue;
            float4 o;
            float* oc = (float*)&o;
            #pragma unroll
            for (int j = 0; j < 4; ++j) {
                const int cc = cb + c0 + j;
                float v = acc[i][4 * j4 + j];
                if (cc < N_REAL) {
                    v += bias[cc];
                    if constexpr (BIAS2) v += bias2[cc];
                    if constexpr (RELU_OUT) v = fmaxf(v, 0.f);
                } else {
                    v = 0.f;
                }
                oc[j] = v;
            }
            *(float4*)&Out[obase + c0] = o;
        }
    }
}

// ---------------------------------------------------------------------------
// LSTM recurrence v3: 64 blocks x 128 threads (2 waves, 1 per SIMD -> 512-reg
// budget each). Lane e (<100) owns element e and computes ALL FOUR gates:
// 400 weight floats pinned per lane (AGPR-resident, VALU-readable on gfx950).
// LDS per step: 25 b128 h-broadcasts per wave (50/CU, was 175/CU) + 1 b32
// write; no gate exchange at all (c,h update lane-local); one raw barrier
// (lgkmcnt only -- global prefetch stays in flight).
// ---------------------------------------------------------------------------
#define FOR25(M) M(0) M(1) M(2) M(3) M(4) M(5) M(6) M(7) M(8) M(9) M(10) M(11) \
                 M(12) M(13) M(14) M(15) M(16) M(17) M(18) M(19) M(20) M(21) M(22) M(23) M(24)

__global__ __launch_bounds__(128, 1) void lstm_rec(
    const float* __restrict__ xg,    // [B, T, 400] (biases pre-added)
    const float* __restrict__ W_hh,  // [400, 100]
    float* __restrict__ hout)        // [B, T, 100]
{
    __shared__ float h_lds[2][104];
    const int e  = threadIdx.x;
    const int ec = (e < H_) ? e : (H_ - 1);
    const bool act_lane = (e < H_);
    const float* xgb = xg + (long)blockIdx.x * T_ * G_ + ec;
    float* hb = hout + (long)blockIdx.x * T_ * H_;

    const float4* wp0 = (const float4*)(W_hh + (0 * H_ + ec) * H_);
    const float4* wp1 = (const float4*)(W_hh + (1 * H_ + ec) * H_);
    const float4* wp2 = (const float4*)(W_hh + (2 * H_ + ec) * H_);
    const float4* wp3 = (const float4*)(W_hh + (3 * H_ + ec) * H_);
#define DECLW4(i) \
    float4 w0_##i = wp0[i]; KEEP4(w0_##i); float4 w1_##i = wp1[i]; KEEP4(w1_##i); \
    float4 w2_##i = wp2[i]; KEEP4(w2_##i); float4 w3_##i = wp3[i]; KEEP4(w3_##i);
    FOR25(DECLW4)

    if (act_lane) h_lds[0][e] = 0.f;
    float c = 0.f;

    float4 p, q;
    p.x = xgb[0];            p.y = xgb[H_];            p.z = xgb[2*H_];            p.w = xgb[3*H_];
    q.x = xgb[G_];           q.y = xgb[G_+H_];         q.z = xgb[G_+2*H_];         q.w = xgb[G_+3*H_];
    __syncthreads();   // once: h init + initial prefetch drain

#define KSTEP(i) { float4 hv = *(const float4*)&hr[4*(i)]; \
    ac0.x = fmaf(w0_##i.x, hv.x, ac0.x); ac0.y = fmaf(w0_##i.y, hv.y, ac0.y); \
    ac0.z = fmaf(w0_##i.z, hv.z, ac0.z); ac0.w = fmaf(w0_##i.w, hv.w, ac0.w); \
    ac1.x = fmaf(w1_##i.x, hv.x, ac1.x); ac1.y = fmaf(w1_##i.y, hv.y, ac1.y); \
    ac1.z = fmaf(w1_##i.z, hv.z, ac1.z); ac1.w = fmaf(w1_##i.w, hv.w, ac1.w); \
    ac2.x = fmaf(w2_##i.x, hv.x, ac2.x); ac2.y = fmaf(w2_##i.y, hv.y, ac2.y); \
    ac2.z = fmaf(w2_##i.z, hv.z, ac2.z); ac2.w = fmaf(w2_##i.w, hv.w, ac2.w); \
    ac3.x = fmaf(w3_##i.x, hv.x, ac3.x); ac3.y = fmaf(w3_##i.y, hv.y, ac3.y); \
    ac3.z = fmaf(w3_##i.z, hv.z, ac3.z); ac3.w = fmaf(w3_##i.w, hv.w, ac3.w); }

#define STEP(PV, TIDX, RB, WB) { \
    const float* hr = &h_lds[RB][0]; \
    float4 ac0 = {PV.x, 0.f, 0.f, 0.f}; float4 ac1 = {PV.y, 0.f, 0.f, 0.f}; \
    float4 ac2 = {PV.z, 0.f, 0.f, 0.f}; float4 ac3 = {PV.w, 0.f, 0.f, 0.f}; \
    FOR25(KSTEP) \
    float g0 = (ac0.x + ac0.y) + (ac0.z + ac0.w); \
    float g1 = (ac1.x + ac1.y) + (ac1.z + ac1.w); \
    float g2 = (ac2.x + ac2.y) + (ac2.z + ac2.w); \
    float g3 = (ac3.x + ac3.y) + (ac3.z + ac3.w); \
    float gi = sigmoid_f(g0), gf = sigmoid_f(g1), go = sigmoid_f(g3); \
    float gt = fmaf(2.f, sigmoid_f(2.f * g2), -1.f);   /* tanh */ \
    c = fmaf(gf, c, gi * gt); \
    float hv2 = go * tanh_safe(c); \
    if (act_lane) { h_lds[WB][e] = hv2; hb[(long)(TIDX) * H_ + e] = hv2; } \
    asm volatile("s_waitcnt lgkmcnt(0)" ::: "memory"); \
    __builtin_amdgcn_s_barrier(); \
    asm volatile("" ::: "memory"); }

    for (int t = 0; t < T_; t += 2) {
        float4 r4 = make_float4(0.f, 0.f, 0.f, 0.f);
        float4 s4 = make_float4(0.f, 0.f, 0.f, 0.f);
        if (t + 2 < T_) {
            const long o = (long)(t + 2) * G_;
            r4.x = xgb[o]; r4.y = xgb[o + H_]; r4.z = xgb[o + 2*H_]; r4.w = xgb[o + 3*H_];
        }
        if (t + 3 < T_) {
            const long o = (long)(t + 3) * G_;
            s4.x = xgb[o]; s4.y = xgb[o + H_]; s4.z = xgb[o + 2*H_]; s4.w = xgb[o + 3*H_];
        }
        STEP(p, t,     0, 1)
        STEP(q, t + 1, 1, 0)
        p = r4; q = s4;
    }
#undef STEP
#undef KSTEP
}

// ---------------------------------------------------------------------------
extern "C" void kernel_launch(void* const* d_in, const int* in_sizes, int n_in,
                              void* d_out, int out_size, void* d_ws, size_t ws_size,
                              hipStream_t stream) {
    const float* x     = (const float*)d_in[0];
    // d_in[1] = y (unused by the reference output)
    const float* W_ih  = (const float*)d_in[2];
    const float* W_hh  = (const float*)d_in[3];
    const float* b_ih  = (const float*)d_in[4];
    const float* b_hh  = (const float*)d_in[5];
    const float* ff1_w = (const float*)d_in[6];
    const float* ff1_b = (const float*)d_in[7];
    const float* ff2_w = (const float*)d_in[8];
    const float* ff2_b = (const float*)d_in[9];
    float* out = (float*)d_out;

    float* xg    = (float*)d_ws;                 // [131072, 400] = 209.7 MB
    float* hbuf  = xg + M_ * G_;                 // [131072, 100] =  52.4 MB
    float* g_ffn = xg;   // reuse: xg fully consumed by lstm_rec before C1 runs
                         // [131072, 384] (cols 300..383 zero-filled) = 201 MB

    // A: xg = x @ W_ih^T + (b_ih + b_hh)      M x 400, K=128
    gemm128<128, 32, 128, 128, 400, 400, 128, false, false, true, true>
        <<<dim3(1024, 4), 256, 0, stream>>>(x, W_ih, b_ih, b_hh, xg);

    // B: recurrence
    lstm_rec<<<B_, 128, 0, stream>>>(xg, W_hh, hbuf);

    // C1: g_ffn = relu(relu(h) @ ff1^T + b1)  M x 300 (padded 384), K=100
    gemm128<100, 20, 100, 100, 384, 300, 100, true, true, false, false>
        <<<dim3(1024, 3), 256, 0, stream>>>(hbuf, ff1_w, ff1_b, nullptr, g_ffn);

    // C2: out = g_ffn @ ff2^T + b2            M x 128, K=300 (padded 320)
    gemm128<320, 32, 384, 300, 128, 128, 300, false, false, false, false>
        <<<dim3(1024, 1), 256, 0, stream>>>(g_ffn, ff2_w, ff2_b, nullptr, out);
}

// Round 7
// 2943.250 us; speedup vs baseline: 1.9314x; 1.9314x over previous
//
#include <hip/hip_runtime.h>
#include <math.h>

// Problem constants: B=64, T=2048, D=128, H=100, F=300
constexpr int H_ = 100;
constexpr int D_ = 128;
constexpr int F_ = 300;
constexpr int T_ = 2048;
constexpr int B_ = 64;
constexpr int G_ = 4 * H_;   // 400 gate rows
constexpr long M_ = (long)B_ * T_;   // 131072 rows

#define KEEP4(v) asm volatile("" : "+v"(v.x), "+v"(v.y), "+v"(v.z), "+v"(v.w))

#define FOR25(M) M(0) M(1) M(2) M(3) M(4) M(5) M(6) M(7) M(8) M(9) M(10) M(11) \
                 M(12) M(13) M(14) M(15) M(16) M(17) M(18) M(19) M(20) M(21) M(22) M(23) M(24)

static __device__ __forceinline__ float fast_rcp(float x) {
    return __builtin_amdgcn_rcpf(x);
}
static __device__ __forceinline__ float sigmoid_f(float u) {
    return fast_rcp(1.f + __expf(-u));   // inf-safe both directions
}
static __device__ __forceinline__ float tanh_safe(float c) {
    return fmaf(-2.f, fast_rcp(__expf(2.f * c) + 1.f), 1.f);
}

// ---------------------------------------------------------------------------
// Generic 128x128-tile f32 GEMM:  Out[m, n] = act( A[m,:K] . W[n,:K] + bias )
// 256 threads = 4 waves (2x2), lane tile 8x8. Operands staged TRANSPOSED in
// LDS so fragment reads are contiguous b128 (distinct-address, conflict-free).
// ---------------------------------------------------------------------------
template<int KTOT, int KB, int IN_LD, int W_LD, int OUT_LD, int N_REAL,
         int WK_REAL, bool RELU_IN, bool RELU_OUT, bool SKIP_PAD_WRITE, bool BIAS2>
__global__ __launch_bounds__(256, 2) void gemm128(
    const float* __restrict__ Ain, const float* __restrict__ Wm,
    const float* __restrict__ bias, const float* __restrict__ bias2,
    float* __restrict__ Out)
{
    __shared__ float as[KB][132];
    __shared__ float bs[KB][132];
    const int tid  = threadIdx.x;
    const int lane = tid & 63;
    const int wave = tid >> 6;
    const int row0 = (wave >> 1) * 64 + (lane >> 3) * 8;  // within block tile
    const int col0 = (wave & 1) * 64 + (lane & 7) * 8;
    const long rb  = (long)blockIdx.x * 128;
    const int  cb  = blockIdx.y * 128;
    constexpr int K4 = KB / 4;

    float acc[8][8];
    #pragma unroll
    for (int i = 0; i < 8; ++i)
        #pragma unroll
        for (int j = 0; j < 8; ++j) acc[i][j] = 0.f;

    for (int kb = 0; kb < KTOT; kb += KB) {
        // stage A tile transposed: as[k][row]
        for (int idx = tid; idx < 128 * K4; idx += 256) {
            int row = idx / K4, k4 = idx % K4;
            float4 v = *(const float4*)&Ain[(rb + row) * (long)IN_LD + kb + 4 * k4];
            if constexpr (RELU_IN) {
                v.x = fmaxf(v.x, 0.f); v.y = fmaxf(v.y, 0.f);
                v.z = fmaxf(v.z, 0.f); v.w = fmaxf(v.w, 0.f);
            }
            as[4*k4+0][row] = v.x; as[4*k4+1][row] = v.y;
            as[4*k4+2][row] = v.z; as[4*k4+3][row] = v.w;
        }
        // stage W tile transposed: bs[k][col], zero-fill col/k padding
        for (int idx = tid; idx < 128 * K4; idx += 256) {
            int col = idx / K4, k4 = idx % K4;
            int gc = cb + col;
            float4 v = make_float4(0.f, 0.f, 0.f, 0.f);
            if (gc < N_REAL && (WK_REAL == KTOT || kb + 4 * k4 < WK_REAL))
                v = *(const float4*)&Wm[(long)gc * W_LD + kb + 4 * k4];
            bs[4*k4+0][col] = v.x; bs[4*k4+1][col] = v.y;
            bs[4*k4+2][col] = v.z; bs[4*k4+3][col] = v.w;
        }
        __syncthreads();

        #pragma unroll
        for (int k = 0; k < KB; ++k) {
            float4 a0 = *(const float4*)&as[k][row0];
            float4 a1 = *(const float4*)&as[k][row0 + 4];
            float4 b0 = *(const float4*)&bs[k][col0];
            float4 b1 = *(const float4*)&bs[k][col0 + 4];
            const float av[8] = {a0.x, a0.y, a0.z, a0.w, a1.x, a1.y, a1.z, a1.w};
            const float bv[8] = {b0.x, b0.y, b0.z, b0.w, b1.x, b1.y, b1.z, b1.w};
            #pragma unroll
            for (int i = 0; i < 8; ++i)
                #pragma unroll
                for (int j = 0; j < 8; ++j)
                    acc[i][j] = fmaf(av[i], bv[j], acc[i][j]);
        }
        __syncthreads();
    }

    // epilogue: bias (+bias2), optional relu; pad cols write 0 (or skip)
    #pragma unroll
    for (int i = 0; i < 8; ++i) {
        const long obase = (rb + row0 + i) * (long)OUT_LD + cb;
        #pragma unroll
        for (int j4 = 0; j4 < 2; ++j4) {
            const int c0 = col0 + 4 * j4;
            if (SKIP_PAD_WRITE && (cb + c0) >= N_REAL) continue;
            float4 o;
            float* oc = (float*)&o;
            #pragma unroll
            for (int j = 0; j < 4; ++j) {
                const int cc = cb + c0 + j;
                float v = acc[i][4 * j4 + j];
                if (cc < N_REAL) {
                    v += bias[cc];
                    if constexpr (BIAS2) v += bias2[cc];
                    if constexpr (RELU_OUT) v = fmaxf(v, 0.f);
                } else {
                    v = 0.f;
                }
                oc[j] = v;
            }
            *(float4*)&Out[obase + c0] = o;
        }
    }
}

// ---------------------------------------------------------------------------
// LSTM recurrence v4: 64 blocks x 256 threads (4 waves). Reuse R=2:
// lane tid<100  owns gate rows (i_e, g_e),  e = tid
// lane tid<200  owns gate rows (f_e, o_e),  e = tid-100
// 200 f32 weights/lane in ~240 VGPRs (fits the 256 arch-VGPR cap; 400 did
// not -> round-5 spill). h broadcast: 25 ds_read_b128 per wave x 4 waves =
// 100/step (was 175). Gate exchange: one b64 LDS write/read (f,o) -> no
// shuffles. Two raw lgkm-only barriers/step; xg prefetch 2 steps deep stays
// in flight across barriers.
// ---------------------------------------------------------------------------
#define DECLWAB(i) float4 wa_##i = wa[i]; KEEP4(wa_##i); \
                   float4 wb_##i = wb[i]; KEEP4(wb_##i);

#define DOTI(i) { float4 hv = *(const float4*)&hr[4*(i)];                    \
    a0 = fmaf(wa_##i.x, hv.x, a0); a1 = fmaf(wa_##i.y, hv.y, a1);            \
    a0 = fmaf(wa_##i.z, hv.z, a0); a1 = fmaf(wa_##i.w, hv.w, a1);            \
    b0 = fmaf(wb_##i.x, hv.x, b0); b1 = fmaf(wb_##i.y, hv.y, b1);            \
    b0 = fmaf(wb_##i.z, hv.z, b0); b1 = fmaf(wb_##i.w, hv.w, b1); }

__global__ __launch_bounds__(256, 1) void lstm_rec(
    const float* __restrict__ xg,    // [B, T, 400] (biases pre-added)
    const float* __restrict__ W_hh,  // [400, 100]
    float* __restrict__ hout)        // [B, T, 100]
{
    __shared__ float  h_lds[2][104];
    __shared__ float2 gex[104];
    const int tid = threadIdx.x;
    const bool act  = (tid < 200);
    const int  grp  = (tid >= 100) ? 1 : 0;          // 0: (i,g)  1: (f,o)
    const int  e    = act ? (tid - grp * 100) : 0;   // element 0..99
    const bool wrtr = act && (grp == 0);
    const int  j1   = grp * 100 + e;                 // i or f row
    const int  j2   = 200 + grp * 100 + e;           // g or o row
    const float* xgb = xg + (long)blockIdx.x * T_ * G_;
    float* hb = hout + (long)blockIdx.x * T_ * H_;

    const float4* wa = (const float4*)(W_hh + (long)j1 * H_);
    const float4* wb = (const float4*)(W_hh + (long)j2 * H_);
    FOR25(DECLWAB)                    // wa_0..24, wb_0..24 pinned (200 VGPR)

    if (tid < H_) h_lds[0][tid] = 0.f;
    float c = 0.f;

    float p1a = act ? xgb[0 * G_ + j1] : 0.f, p1b = act ? xgb[0 * G_ + j2] : 0.f;
    float p2a = act ? xgb[1 * G_ + j1] : 0.f, p2b = act ? xgb[1 * G_ + j2] : 0.f;
    __syncthreads();   // once: h init + initial prefetch drain

#define BARRIER_LGKM() do {                                                  \
        asm volatile("s_waitcnt lgkmcnt(0)" ::: "memory");                   \
        __builtin_amdgcn_s_barrier();                                        \
        asm volatile("" ::: "memory");                                       \
    } while (0)

#define STEP(PA, PB, TIDX, RB, WB) {                                         \
        const float* hr = &h_lds[RB][0];                                     \
        float a0 = (PA), a1 = 0.f, b0 = (PB), b1 = 0.f;                      \
        FOR25(DOTI)                                                          \
        float ga = a0 + a1, gb = b0 + b1;                                    \
        float va = sigmoid_f(ga);          /* sigma(i) or sigma(f) */        \
        float vb = (grp == 0) ? fmaf(2.f, sigmoid_f(2.f * gb), -1.f)         \
                              : sigmoid_f(gb);   /* tanh(g) or sigma(o) */   \
        if (act && grp) gex[e] = make_float2(va, vb);   /* {f, o} */         \
        BARRIER_LGKM();                                                      \
        if (wrtr) {                                                          \
            float2 fo = gex[e];                                              \
            c = fmaf(fo.x, c, va * vb);                                      \
            float hv = fo.y * tanh_safe(c);                                  \
            h_lds[WB][e] = hv;                                               \
            hb[(long)(TIDX) * H_ + e] = hv;                                  \
        }                                                                    \
        BARRIER_LGKM();                                                      \
    }

    for (int t = 0; t < T_; t += 2) {
        float n1a = 0.f, n1b = 0.f, n2a = 0.f, n2b = 0.f;
        if (act && t + 2 < T_) {
            n1a = xgb[(long)(t + 2) * G_ + j1];
            n1b = xgb[(long)(t + 2) * G_ + j2];
        }
        if (act && t + 3 < T_) {
            n2a = xgb[(long)(t + 3) * G_ + j1];
            n2b = xgb[(long)(t + 3) * G_ + j2];
        }
        STEP(p1a, p1b, t,     0, 1)
        STEP(p2a, p2b, t + 1, 1, 0)
        p1a = n1a; p1b = n1b; p2a = n2a; p2b = n2b;
    }
#undef STEP
#undef BARRIER_LGKM
}

// ---------------------------------------------------------------------------
extern "C" void kernel_launch(void* const* d_in, const int* in_sizes, int n_in,
                              void* d_out, int out_size, void* d_ws, size_t ws_size,
                              hipStream_t stream) {
    const float* x     = (const float*)d_in[0];
    // d_in[1] = y (unused by the reference output)
    const float* W_ih  = (const float*)d_in[2];
    const float* W_hh  = (const float*)d_in[3];
    const float* b_ih  = (const float*)d_in[4];
    const float* b_hh  = (const float*)d_in[5];
    const float* ff1_w = (const float*)d_in[6];
    const float* ff1_b = (const float*)d_in[7];
    const float* ff2_w = (const float*)d_in[8];
    const float* ff2_b = (const float*)d_in[9];
    float* out = (float*)d_out;

    float* xg    = (float*)d_ws;                 // [131072, 400] = 209.7 MB
    float* hbuf  = xg + M_ * G_;                 // [131072, 100] =  52.4 MB
    float* g_ffn = xg;   // reuse: xg fully consumed by lstm_rec before C1 runs
                         // [131072, 384] (cols 300..383 zero-filled) = 201 MB

    // A: xg = x @ W_ih^T + (b_ih + b_hh)      M x 400, K=128
    gemm128<128, 32, 128, 128, 400, 400, 128, false, false, true, true>
        <<<dim3(1024, 4), 256, 0, stream>>>(x, W_ih, b_ih, b_hh, xg);

    // B: recurrence
    lstm_rec<<<B_, 256, 0, stream>>>(xg, W_hh, hbuf);

    // C1: g_ffn = relu(relu(h) @ ff1^T + b1)  M x 300 (padded 384), K=100
    gemm128<100, 20, 100, 100, 384, 300, 100, true, true, false, false>
        <<<dim3(1024, 3), 256, 0, stream>>>(hbuf, ff1_w, ff1_b, nullptr, g_ffn);

    // C2: out = g_ffn @ ff2^T + b2            M x 128, K=300 (padded 320)
    gemm128<320, 32, 384, 300, 128, 128, 300, false, false, false, false>
        <<<dim3(1024, 1), 256, 0, stream>>>(g_ffn, ff2_w, ff2_b, nullptr, out);
}